// Round 8
// baseline (1615.773 us; speedup 1.0000x reference)
//
#include <hip/hip_runtime.h>
#include <hip/hip_bf16.h>
#include <stdint.h>

// Problem constants
#define NN 100000   // nodes
#define RR 200      // relations
#define DD 200      // dim
#define BB 30       // bases
#define LL 2        // layers
#define EE 800000   // edges

// Padded GEMM geometry
#define KP 224      // K padded (7 x 32)
#define NP 208      // N padded (13 x 16)
#define XP 224      // xb row pitch (bf16) = 448B = 7 aligned lines, zero-padded cols 200..223
#define AP 232      // LDS A-tile pitch (kRootGemm only)
#define TE 64       // edges per kMsg tile (1 M-frag per wave, 4 waves)
#define RT 128      // rows per kRootGemm tile
#define MSGP 200    // msg row pitch (bf16) -> 400B
#define MAXTILES 12700
#define MAXNC 24
#define NPART 128   // partition blocks for the 2-pass sort
#define EPB ((EE + NPART - 1) / NPART)   // 6250 edges per partition

using bf16x8 = __attribute__((ext_vector_type(8))) short;
using f32x4  = __attribute__((ext_vector_type(4))) float;

// Workspace layout. Fallback path touches only < OFF_CTL.
#define OFF_NORM   0ull          // E f32
#define OFF_SORT   3200000ull    // E i32
#define OFF_CNT    6400000ull    // 4KB ctl (fallback)
#define OFF_XB     6404096ull    // N*XP bf16 = 44.8MB (deg8 20MB aliases transiently)
#define OFF_WT     51204096ull   // R*NP*KP bf16 = 18,636,800
#define OFF_ROOTT  69840896ull   // NP*KP bf16 = 93,184
#define OFF_CTL    69934080ull   // 128KB ctl (big)
#define OFF_POS    70065152ull   // E i32
#define OFF_DSTCNT 73265152ull   // N i32
#define OFF_DSTST  73665152ull   // (N+1) i32 (+pad)
#define OFF_CUR    74065184ull   // N i32
#define OFF_BLKH   74465184ull   // NPART * NC*RR i32 (dynamic) ; msg follows

static __device__ __forceinline__ short f2bf(float v) {
    union { __hip_bfloat16 h; short s; } u;
    u.h = __float2bfloat16(v);
    return u.s;
}

// ---- deg per (dst,rel) + per-dst histogram ----
__global__ void kCount(const int* __restrict__ ei, const int* __restrict__ et,
                       unsigned int* __restrict__ deg8, int* __restrict__ dstCnt, int big) {
    int e = blockIdx.x * 256 + threadIdx.x;
    if (e >= EE) return;
    int d = ei[EE + e];
    int t = et[e];
    int comb = d * RR + t;
    atomicAdd(&deg8[comb >> 2], 1u << ((comb & 3) * 8));
    if (big) atomicAdd(&dstCnt[d], 1);
}

// ---- 3-kernel exclusive scan of dstCnt[N] -> dstStart[N+1] ----
__global__ void kScanBlk(const int* __restrict__ dstCnt, int* __restrict__ dstStart,
                         int* __restrict__ blkSum) {
    __shared__ int s[256];
    int t = threadIdx.x, i = blockIdx.x * 256 + t;
    int v = (i < NN) ? dstCnt[i] : 0;
    s[t] = v;
    __syncthreads();
    #pragma unroll
    for (int off = 1; off < 256; off <<= 1) {
        int x = (t >= off) ? s[t - off] : 0;
        __syncthreads();
        s[t] += x;
        __syncthreads();
    }
    if (i < NN) dstStart[i] = s[t] - v;
    if (t == 255) blkSum[blockIdx.x] = s[255];
}
__global__ void kScanTop(int* __restrict__ blkSum, int nblk) {
    __shared__ int s[512];
    int t = threadIdx.x;
    int v = (t < nblk) ? blkSum[t] : 0;
    s[t] = v;
    __syncthreads();
    #pragma unroll
    for (int off = 1; off < 512; off <<= 1) {
        int x = (t >= off) ? s[t - off] : 0;
        __syncthreads();
        s[t] += x;
        __syncthreads();
    }
    if (t < nblk) blkSum[t] = s[t] - v;
}
__global__ void kScanAdd(const int* __restrict__ dstCnt, int* __restrict__ dstStart,
                         const int* __restrict__ blkSum) {
    int i = blockIdx.x * 256 + threadIdx.x;
    if (i >= NN) return;
    int v = dstStart[i] + blkSum[blockIdx.x];
    dstStart[i] = v;
    if (i == NN - 1) dstStart[NN] = v + dstCnt[i];
}

// ---- chunk boundaries: b[c] = smallest node with dstStart >= c*T ----
__global__ void kChunk(const int* __restrict__ dstStart, int* __restrict__ bS,
                       int* __restrict__ cesS, int NC, int T) {
    int tid = threadIdx.x;
    if (tid > NC) return;
    int v;
    if (tid == NC) v = NN;
    else if (tid == 0) v = 0;
    else {
        int target = tid * T;
        int lo = 0, hi = NN;
        while (lo < hi) {
            int mid = (lo + hi) >> 1;
            if (dstStart[mid] >= target) hi = mid; else lo = mid + 1;
        }
        v = lo;
    }
    bS[tid] = v;
    cesS[tid] = dstStart[v];
}

// ---- PASS 1: per-partition LDS histogram of (chunk,rel) buckets ----
__global__ __launch_bounds__(256) void kHist(const int* __restrict__ ei,
        const int* __restrict__ et, const int* __restrict__ bS,
        int* __restrict__ blockHist, int NC) {
    __shared__ int hist[MAXNC * RR];
    __shared__ int bsh[MAXNC + 1];
    int tid = threadIdx.x, b = blockIdx.x;
    int NB = NC * RR;
    if (tid <= NC) bsh[tid] = bS[tid];
    for (int i = tid; i < NB; i += 256) hist[i] = 0;
    __syncthreads();
    int ebeg = b * EPB, eend = min(EE, ebeg + EPB);
    for (int e = ebeg + tid; e < eend; e += 256) {
        int d = ei[EE + e];
        int t = et[e];
        int c = 0;
        for (int j = 1; j < NC; ++j) if (d >= bsh[j]) c = j;
        atomicAdd(&hist[c * RR + t], 1);
    }
    __syncthreads();
    for (int i = tid; i < NB; i += 256)
        blockHist[(size_t)b * NB + i] = hist[i];
}

// ---- PASS 1b: per-bucket exclusive scan across partitions; totals -> cntB ----
__global__ __launch_bounds__(128) void kScanP(int* __restrict__ blockHist,
                                              int* __restrict__ cntB, int NB) {
    __shared__ int s[NPART];
    int t = threadIdx.x, k = blockIdx.x;
    int v = blockHist[(size_t)t * NB + k];
    s[t] = v;
    __syncthreads();
    #pragma unroll
    for (int off = 1; off < NPART; off <<= 1) {
        int x = (t >= off) ? s[t - off] : 0;
        __syncthreads();
        s[t] += x;
        __syncthreads();
    }
    blockHist[(size_t)t * NB + k] = s[t] - v;
    if (t == NPART - 1) cntB[k] = s[NPART - 1];
}

// ---- bucket scan (nb <= 4800) ----
__global__ void kScanB(const int* __restrict__ cntB, int* __restrict__ relStartB,
                       int* __restrict__ cursorB, int* __restrict__ tileOffB, int nb) {
    __shared__ int c[MAXNC * RR];
    __shared__ int rs[MAXNC * RR + 1];
    __shared__ int to[MAXNC * RR + 1];
    int tid = threadIdx.x;
    for (int i = tid; i < nb; i += 256) c[i] = cntB[i];
    __syncthreads();
    if (tid == 0) {
        int s = 0, ts = 0;
        for (int i = 0; i < nb; ++i) {
            rs[i] = s; to[i] = ts;
            s += c[i];
            ts += (c[i] + TE - 1) / TE;
        }
        rs[nb] = s; to[nb] = ts;
    }
    __syncthreads();
    for (int i = tid; i <= nb; i += 256) {
        relStartB[i] = rs[i];
        tileOffB[i]  = to[i];
        if (i < nb) cursorB[i] = rs[i];
    }
}

// ---- PASS 2: partition scatter with LDS cursors; norm + posDst fused ----
__global__ __launch_bounds__(256) void kPart(const int* __restrict__ ei,
        const int* __restrict__ et, const unsigned int* __restrict__ deg8,
        const int* __restrict__ bS, const int* __restrict__ relStartB,
        const int* __restrict__ blockHist, const int* __restrict__ dstStart,
        int* __restrict__ cur, float* __restrict__ norm, int* __restrict__ sortedE,
        int* __restrict__ posDst, int NC) {
    __shared__ int curL[MAXNC * RR];
    __shared__ int bsh[MAXNC + 1];
    int tid = threadIdx.x, b = blockIdx.x;
    int NB = NC * RR;
    if (tid <= NC) bsh[tid] = bS[tid];
    for (int i = tid; i < NB; i += 256)
        curL[i] = relStartB[i] + blockHist[(size_t)b * NB + i];
    __syncthreads();
    int ebeg = b * EPB, eend = min(EE, ebeg + EPB);
    for (int e = ebeg + tid; e < eend; e += 256) {
        int d = ei[EE + e];
        int t = et[e];
        int comb = d * RR + t;
        unsigned int deg = (deg8[comb >> 2] >> ((comb & 3) * 8)) & 0xffu;
        norm[e] = 1.0f / (float)(deg ? deg : 1u);
        int c = 0;
        for (int j = 1; j < NC; ++j) if (d >= bsh[j]) c = j;
        int pos = atomicAdd(&curL[c * RR + t], 1);
        sortedE[pos] = e;
        posDst[e] = dstStart[d] + atomicAdd(&cur[d], 1);
    }
}

// ---- fallback-only: (chunk, rel) bucket histogram via global atomics ----
__global__ void kCountB(const int* __restrict__ ei, const int* __restrict__ et,
                        const int* __restrict__ bS, int* __restrict__ cntB, int NC) {
    __shared__ int bsh[MAXNC + 1];
    if (threadIdx.x <= NC) bsh[threadIdx.x] = bS[threadIdx.x];
    __syncthreads();
    int e = blockIdx.x * 256 + threadIdx.x;
    if (e >= EE) return;
    int d = ei[EE + e];
    int t = et[e];
    int c = 0;
    for (int j = 1; j < NC; ++j) if (d >= bsh[j]) c = j;
    atomicAdd(&cntB[c * RR + t], 1);
}

// ---- fallback-only: per-edge norm + counting-sort via global cursors ----
__global__ void kNormScatter(const int* __restrict__ ei, const int* __restrict__ et,
                             const unsigned int* __restrict__ deg8, const int* __restrict__ bS,
                             int* __restrict__ cursorB, const int* __restrict__ dstStart,
                             int* __restrict__ cur, float* __restrict__ norm,
                             int* __restrict__ sortedE, int* __restrict__ posDst,
                             int NC, int big) {
    __shared__ int bsh[MAXNC + 1];
    if (threadIdx.x <= NC) bsh[threadIdx.x] = bS[threadIdx.x];
    __syncthreads();
    int e = blockIdx.x * 256 + threadIdx.x;
    if (e >= EE) return;
    int d = ei[EE + e];
    int t = et[e];
    int comb = d * RR + t;
    unsigned int deg = (deg8[comb >> 2] >> ((comb & 3) * 8)) & 0xffu;
    norm[e] = 1.0f / (float)(deg ? deg : 1u);
    int c = 0;
    for (int j = 1; j < NC; ++j) if (d >= bsh[j]) c = j;
    int pos = atomicAdd(&cursorB[c * RR + t], 1);
    sortedE[pos] = e;
    if (big) posDst[e] = dstStart[d] + atomicAdd(&cur[d], 1);
}

// ---- fp32 [N,DD] -> bf16 [N,XP] (cols >= DD zeroed) ----
__global__ void kConvert(const float* __restrict__ x, short* __restrict__ xb, int doRelu) {
    int idx = blockIdx.x * 256 + threadIdx.x;
    if (idx >= NN * XP) return;
    int i = idx / XP, col = idx - i * XP;
    float v = 0.0f;
    if (col < DD) {
        v = x[i * DD + col];
        if (doRelu) v = fmaxf(v, 0.0f);
    }
    xb[idx] = (col < DD) ? f2bf(v) : (short)0;
}

__global__ void kRelu(float* __restrict__ y) {
    int idx = blockIdx.x * 256 + threadIdx.x;
    if (idx < NN * DD) y[idx] = fmaxf(y[idx], 0.0f);
}

// ---- Wt[r][n][k] = sum_b comp[r][b]*bases[b][k][n]; load-once-per-cell ----
__global__ __launch_bounds__(256) void kW(const float* __restrict__ comp,
                                          const float* __restrict__ bases,
                                          short* __restrict__ Wt) {
    int kt = blockIdx.x;                  // 0..6
    int ng = blockIdx.y;                  // 0..25
    int tid = threadIdx.x;
    int k = kt * 32 + (tid & 31);
    int n = ng * 8 + (tid >> 5);
    bool live = (k < DD) && (n < DD);
    float vb[BB];
    #pragma unroll
    for (int b = 0; b < BB; ++b)
        vb[b] = live ? bases[((size_t)b * DD + k) * DD + n] : 0.0f;
    size_t wo = (size_t)n * KP + k;
    for (int r = 0; r < RR; ++r) {
        float a = 0.0f;
        #pragma unroll
        for (int b = 0; b < BB; ++b) a += comp[r * BB + b] * vb[b];
        Wt[(size_t)r * (NP * KP) + wo] = f2bf(a);
    }
}

// ---- rootT[n][k] = root[k][n] ----
__global__ void kRootT(const float* __restrict__ root, short* __restrict__ rootT) {
    int idx = blockIdx.x * 256 + threadIdx.x;
    if (idx >= NP * KP) return;
    int n = idx / KP, k = idx - n * KP;
    rootT[idx] = (n < DD && k < DD) ? f2bf(root[k * DD + n]) : (short)0;
}

// ---- inner GEMM for kRootGemm: 2 M-frags x NF N-frags, kc-double-buffered B ----
template<int F0, int NF>
__device__ __forceinline__ void gemmHalf2(const short* As, const short* bCol,
                                          int arow0, int arow1, int kg,
                                          f32x4* acc0, f32x4* acc1) {
    #pragma unroll
    for (int f = 0; f < NF; ++f) {
        acc0[f] = (f32x4){0.f, 0.f, 0.f, 0.f};
        acc1[f] = (f32x4){0.f, 0.f, 0.f, 0.f};
    }
    bf16x8 bb[2][NF];
    #pragma unroll
    for (int f = 0; f < NF; ++f)
        bb[0][f] = *(const bf16x8*)(bCol + (size_t)(F0 + f) * 16 * KP);
    #pragma unroll
    for (int kc = 0; kc < 7; ++kc) {
        if (kc < 6) {
            #pragma unroll
            for (int f = 0; f < NF; ++f)
                bb[(kc + 1) & 1][f] = *(const bf16x8*)(bCol + (size_t)(F0 + f) * 16 * KP + (kc + 1) * 32);
        }
        bf16x8 a0 = *(const bf16x8*)(&As[arow0 * AP + kc * 32 + kg]);
        bf16x8 a1 = *(const bf16x8*)(&As[arow1 * AP + kc * 32 + kg]);
        #pragma unroll
        for (int f = 0; f < NF; ++f) {
            acc0[f] = __builtin_amdgcn_mfma_f32_16x16x32_bf16(a0, bb[kc & 1][f], acc0[f], 0, 0, 0);
            acc1[f] = __builtin_amdgcn_mfma_f32_16x16x32_bf16(a1, bb[kc & 1][f], acc1[f], 0, 0, 0);
        }
    }
}

// ---- y[i][:] = xb[i][:] @ root + bias  (128 rows/block, 2 M-frags/wave) ----
__global__ __launch_bounds__(256) void kRootGemm(const short* __restrict__ xb,
        const short* __restrict__ rootT, const float* __restrict__ bias,
        float* __restrict__ y) {
    __shared__ short As[RT * AP];
    int i0 = blockIdx.x * RT;
    int tid = threadIdx.x;
    int rowL = tid >> 1, sub = tid & 1;
    int i = i0 + rowL;
    for (int c = sub; c < 28; c += 2) {
        int4 v = make_int4(0, 0, 0, 0);
        if (i < NN) v = *(const int4*)(xb + (size_t)i * XP + c * 8);
        *(int4*)(&As[rowL * AP + c * 8]) = v;
    }
    __syncthreads();
    int lane = tid & 63, wave = tid >> 6;
    int arow0 = wave * 32 + (lane & 15);
    int arow1 = arow0 + 16;
    int kg = (lane >> 4) * 8;
    const short* bCol = rootT + (lane & 15) * KP + kg;
    int colLane = lane & 15;
    int rbase = i0 + wave * 32 + (lane >> 4) * 4;
    {
        f32x4 acc0[7], acc1[7];
        gemmHalf2<0, 7>(As, bCol, arow0, arow1, kg, acc0, acc1);
        #pragma unroll
        for (int f = 0; f < 7; ++f) {
            int col = f * 16 + colLane;
            float bv = bias[col];
            #pragma unroll
            for (int j = 0; j < 4; ++j) {
                int r0 = rbase + j, r1 = rbase + 16 + j;
                if (r0 < NN) y[(size_t)r0 * DD + col] = acc0[f][j] + bv;
                if (r1 < NN) y[(size_t)r1 * DD + col] = acc1[f][j] + bv;
            }
        }
    }
    {
        f32x4 acc0[6], acc1[6];
        gemmHalf2<7, 6>(As, bCol, arow0, arow1, kg, acc0, acc1);
        #pragma unroll
        for (int f = 0; f < 6; ++f) {
            int col = (7 + f) * 16 + colLane;
            if (col < DD) {
                float bv = bias[col];
                #pragma unroll
                for (int j = 0; j < 4; ++j) {
                    int r0 = rbase + j, r1 = rbase + 16 + j;
                    if (r0 < NN) y[(size_t)r0 * DD + col] = acc0[f][j] + bv;
                    if (r1 < NN) y[(size_t)r1 * DD + col] = acc1[f][j] + bv;
                }
            }
        }
    }
}

// ---- per-(bucket,tile) gather-GEMM, LDS-free & barrier-free.
//      Each lane loads its MFMA A-fragment directly from global xb.
//      MODE 0: store msg rows; MODE 1: atomic y ----
template<int MODE>
__global__ __launch_bounds__(256) void kMsg(const int* __restrict__ ei,
        const short* __restrict__ xb, const short* __restrict__ Wt,
        const int* __restrict__ relStartB, const int* __restrict__ tileOffB,
        const int* __restrict__ sortedE, const float* __restrict__ norm,
        const int* __restrict__ posDst, const int* __restrict__ cesS,
        float* __restrict__ y, short* __restrict__ msg, int c) {
    int tbase = tileOffB[c * RR];
    int tend  = tileOffB[(c + 1) * RR];
    int tileIdx = tbase + blockIdx.x;
    if (tileIdx >= tend) return;
    int lo = c * RR, hi = (c + 1) * RR;
    while (hi - lo > 1) {
        int mid = (lo + hi) >> 1;
        if (tileOffB[mid] <= tileIdx) lo = mid; else hi = mid;
    }
    int r = lo - c * RR;
    int eBase = relStartB[lo] + (tileIdx - tileOffB[lo]) * TE;
    int eEnd  = relStartB[lo + 1];
    int tid = threadIdx.x, lane = tid & 63, wave = tid >> 6;
    int stripe = wave * 16;
    int kg = (lane >> 4) * 8;
    int colLane = lane & 15;
    // A fragment: lane owns GEMM row stripe+colLane, cols kg + kc*32
    int eIdxA = eBase + stripe + colLane;
    int eidA = sortedE[min(eIdxA, eEnd - 1)];   // clamped; invalid rows discarded at store
    int srcA = ei[eidA];                        // SOURCE node of the edge
    const short* aRow = xb + (size_t)srcA * XP;
    bf16x8 a[7];
    #pragma unroll
    for (int kc = 0; kc < 7; ++kc)
        a[kc] = *(const bf16x8*)(aRow + kc * 32 + kg);
    // output-row metadata: rows rbase+j
    int rbase = stripe + (lane >> 4) * 4;
    int psv[4]; float nmv[4];
    #pragma unroll
    for (int j = 0; j < 4; ++j) {
        int eI = eBase + rbase + j;
        bool v = eI < eEnd;
        int eid = v ? sortedE[eI] : 0;
        nmv[j] = v ? norm[eid] : 0.0f;
        if (MODE == 0) psv[j] = v ? (posDst[eid] - cesS[c]) : -1;
        else           psv[j] = v ? ei[EE + eid] : -1;
    }
    const short* bCol = Wt + (size_t)r * (NP * KP) + colLane * KP + kg;
    {
        f32x4 acc[7];
        #pragma unroll
        for (int f = 0; f < 7; ++f) acc[f] = (f32x4){0.f, 0.f, 0.f, 0.f};
        bf16x8 bb[2][7];
        #pragma unroll
        for (int f = 0; f < 7; ++f)
            bb[0][f] = *(const bf16x8*)(bCol + (size_t)f * 16 * KP);
        #pragma unroll
        for (int kc = 0; kc < 7; ++kc) {
            if (kc < 6) {
                #pragma unroll
                for (int f = 0; f < 7; ++f)
                    bb[(kc + 1) & 1][f] = *(const bf16x8*)(bCol + (size_t)f * 16 * KP + (kc + 1) * 32);
            }
            #pragma unroll
            for (int f = 0; f < 7; ++f)
                acc[f] = __builtin_amdgcn_mfma_f32_16x16x32_bf16(a[kc], bb[kc & 1][f], acc[f], 0, 0, 0);
        }
        #pragma unroll
        for (int j = 0; j < 4; ++j) {
            int ps = psv[j]; float nm = nmv[j];
            if (ps >= 0) {
                #pragma unroll
                for (int f = 0; f < 7; ++f) {
                    int col = f * 16 + colLane;
                    float val = acc[f][j] * nm;
                    if (MODE == 0) msg[(size_t)ps * MSGP + col] = f2bf(val);
                    else           atomicAdd(&y[(size_t)ps * DD + col], val);
                }
            }
        }
    }
    {
        f32x4 acc[6];
        #pragma unroll
        for (int f = 0; f < 6; ++f) acc[f] = (f32x4){0.f, 0.f, 0.f, 0.f};
        bf16x8 bb[2][6];
        #pragma unroll
        for (int f = 0; f < 6; ++f)
            bb[0][f] = *(const bf16x8*)(bCol + (size_t)(7 + f) * 16 * KP);
        #pragma unroll
        for (int kc = 0; kc < 7; ++kc) {
            if (kc < 6) {
                #pragma unroll
                for (int f = 0; f < 6; ++f)
                    bb[(kc + 1) & 1][f] = *(const bf16x8*)(bCol + (size_t)(7 + f) * 16 * KP + (kc + 1) * 32);
            }
            #pragma unroll
            for (int f = 0; f < 6; ++f)
                acc[f] = __builtin_amdgcn_mfma_f32_16x16x32_bf16(a[kc], bb[kc & 1][f], acc[f], 0, 0, 0);
        }
        #pragma unroll
        for (int j = 0; j < 4; ++j) {
            int ps = psv[j]; float nm = nmv[j];
            if (ps >= 0) {
                #pragma unroll
                for (int f = 0; f < 6; ++f) {
                    int col = (7 + f) * 16 + colLane;
                    if (col < DD) {
                        float val = acc[f][j] * nm;
                        if (MODE == 0) msg[(size_t)ps * MSGP + col] = f2bf(val);
                        else           atomicAdd(&y[(size_t)ps * DD + col], val);
                    }
                }
            }
        }
    }
}

// ---- grid-stride segmented sum over chunk's node range; y = relu(y + sum(msg)) ----
__global__ __launch_bounds__(256) void kAgg(const short* __restrict__ msg,
        const int* __restrict__ dstStart, const int* __restrict__ bS,
        const int* __restrict__ cesS, float* __restrict__ y, int c) {
    int wv = threadIdx.x >> 6, lane = threadIdx.x & 63;
    int b0 = bS[c], b1 = bS[c + 1];
    int ces = cesS[c];
    int gw = blockIdx.x * 4 + wv;
    int nw = gridDim.x * 4;
    for (int d = b0 + gw; d < b1; d += nw) {
        int s = dstStart[d] - ces, e = dstStart[d + 1] - ces;
        float a0 = 0.f, a1 = 0.f, a2 = 0.f, a3 = 0.f;
        if (lane < 50) {
            for (int j = s; j < e; ++j) {
                int2 v = *(const int2*)(msg + (size_t)j * MSGP + lane * 4);
                unsigned u0 = (unsigned)v.x, u1 = (unsigned)v.y;
                a0 += __uint_as_float(u0 << 16);
                a1 += __uint_as_float(u0 & 0xffff0000u);
                a2 += __uint_as_float(u1 << 16);
                a3 += __uint_as_float(u1 & 0xffff0000u);
            }
            int colBase = lane * 4;
            float4 rv = *(const float4*)(y + (size_t)d * DD + colBase);
            float4 o;
            o.x = fmaxf(rv.x + a0, 0.f);
            o.y = fmaxf(rv.y + a1, 0.f);
            o.z = fmaxf(rv.z + a2, 0.f);
            o.w = fmaxf(rv.w + a3, 0.f);
            *(float4*)(y + (size_t)d * DD + colBase) = o;
        }
    }
}

extern "C" void kernel_launch(void* const* d_in, const int* in_sizes, int n_in,
                              void* d_out, int out_size, void* d_ws, size_t ws_size,
                              hipStream_t stream) {
    (void)in_sizes; (void)n_in; (void)out_size;
    const int*   ei    = (const int*)d_in[0];
    const int*   et    = (const int*)d_in[1];
    const float* emb   = (const float*)d_in[2];
    const float* comp  = (const float*)d_in[3];
    const float* bases = (const float*)d_in[4];
    const float* root  = (const float*)d_in[5];
    const float* bias  = (const float*)d_in[6];
    float* y = (float*)d_out;
    char* ws = (char*)d_ws;
    float* norm    = (float*)(ws + OFF_NORM);
    int*   sortedE = (int*)(ws + OFF_SORT);
    short* xb      = (short*)(ws + OFF_XB);
    short* Wt      = (short*)(ws + OFF_WT);
    short* rootT   = (short*)(ws + OFF_ROOTT);
    int*   posDst  = (int*)(ws + OFF_POS);
    int*   dstCnt  = (int*)(ws + OFF_DSTCNT);
    int*   dstStart= (int*)(ws + OFF_DSTST);
    int*   cur     = (int*)(ws + OFF_CUR);
    int*   blockHist = (int*)(ws + OFF_BLKH);
    unsigned int* deg8 = (unsigned int*)(ws + OFF_XB);  // transient alias

    // choose chunk count from available workspace (pure function of ws_size)
    int NC = 0;
    long long T = EE;
    unsigned long long msgOff = 0;
    for (int cc = 1; cc <= MAXNC; ++cc) {
        long long t = (EE + cc - 1) / cc;
        unsigned long long mo = OFF_BLKH + (unsigned long long)NPART * cc * RR * 4;
        unsigned long long need = mo + (unsigned long long)(t + 64) * (MSGP * 2);
        if ((unsigned long long)ws_size >= need) { NC = cc; T = t; msgOff = mo; break; }
    }
    int big = (NC > 0) ? 1 : 0;
    if (!big) { NC = 1; T = EE; msgOff = OFF_BLKH; }
    short* msg = (short*)(ws + msgOff);

    int *cntB, *relStartB, *cursorB, *tileOffB, *bS, *cesS, *blkSum;
    if (big) {
        int* ctl = (int*)(ws + OFF_CTL);
        cntB = ctl; relStartB = ctl + 4864; cursorB = ctl + 9728;
        tileOffB = ctl + 14592; bS = ctl + 19456; cesS = ctl + 19520; blkSum = ctl + 19584;
    } else {
        int* ctl = (int*)(ws + OFF_CNT);
        cntB = ctl; relStartB = ctl + 256; cursorB = ctl + 512;
        tileOffB = ctl + 768; bS = ctl + 976; cesS = ctl + 992; blkSum = ctl + 1000;
    }

    const int NBLK = (NN + 255) / 256;  // 391

    hipMemsetAsync(deg8, 0, (size_t)NN * RR, stream);
    if (big) {
        hipMemsetAsync(dstCnt, 0, (size_t)NN * 4, stream);
        hipMemsetAsync(cur, 0, (size_t)NN * 4, stream);
    } else {
        hipMemsetAsync((void*)cntB, 0, 4096, stream);
    }

    kCount<<<(EE + 255) / 256, 256, 0, stream>>>(ei, et, deg8, dstCnt, big);
    if (big) {
        kScanBlk<<<NBLK, 256, 0, stream>>>(dstCnt, dstStart, blkSum);
        kScanTop<<<1, 512, 0, stream>>>(blkSum, NBLK);
        kScanAdd<<<NBLK, 256, 0, stream>>>(dstCnt, dstStart, blkSum);
        kChunk<<<1, 64, 0, stream>>>(dstStart, bS, cesS, NC, (int)T);
        // contention-free 2-pass counting sort
        kHist<<<NPART, 256, 0, stream>>>(ei, et, bS, blockHist, NC);
        kScanP<<<NC * RR, NPART, 0, stream>>>(blockHist, cntB, NC * RR);
        kScanB<<<1, 256, 0, stream>>>(cntB, relStartB, cursorB, tileOffB, NC * RR);
        kPart<<<NPART, 256, 0, stream>>>(ei, et, deg8, bS, relStartB, blockHist,
                                         dstStart, cur, norm, sortedE, posDst, NC);
    } else {
        kCountB<<<(EE + 255) / 256, 256, 0, stream>>>(ei, et, bS, cntB, NC);
        kScanB<<<1, 256, 0, stream>>>(cntB, relStartB, cursorB, tileOffB, NC * RR);
        kNormScatter<<<(EE + 255) / 256, 256, 0, stream>>>(ei, et, deg8, bS, cursorB,
                                                           dstStart, cur, norm, sortedE,
                                                           posDst, NC, big);
    }
    kConvert<<<(NN * XP + 255) / 256, 256, 0, stream>>>(emb, xb, 0);

    int Gmsg = (int)((T + TE - 1) / TE) + RR + 4;
    for (int l = 0; l < LL; ++l) {
        kW<<<dim3(7, 26), 256, 0, stream>>>(comp + l * RR * BB,
                                            bases + (size_t)l * BB * DD * DD, Wt);
        kRootT<<<(NP * KP + 255) / 256, 256, 0, stream>>>(root + l * DD * DD, rootT);
        kRootGemm<<<(NN + RT - 1) / RT, 256, 0, stream>>>(xb, rootT, bias + l * DD, y);
        if (big) {
            for (int c = 0; c < NC; ++c) {
                kMsg<0><<<Gmsg, 256, 0, stream>>>(ei, xb, Wt, relStartB, tileOffB,
                                                  sortedE, norm, posDst, cesS, y, msg, c);
                kAgg<<<2048, 256, 0, stream>>>(msg, dstStart, bS, cesS, y, c);
            }
            if (l == 0)
                kConvert<<<(NN * XP + 255) / 256, 256, 0, stream>>>(y, xb, 0);
        } else {
            kMsg<1><<<MAXTILES, 256, 0, stream>>>(ei, xb, Wt, relStartB, tileOffB,
                                                  sortedE, norm, posDst, cesS, y, msg, 0);
            if (l == 0) kConvert<<<(NN * XP + 255) / 256, 256, 0, stream>>>(y, xb, 1);
            else        kRelu<<<(NN * DD + 255) / 256, 256, 0, stream>>>(y);
        }
    }
}

// Round 9
// 1293.814 us; speedup vs baseline: 1.2488x; 1.2488x over previous
//
#include <hip/hip_runtime.h>
#include <hip/hip_bf16.h>
#include <stdint.h>

// Problem constants
#define NN 100000   // nodes
#define RR 200      // relations
#define DD 200      // dim
#define BB 30       // bases
#define LL 2        // layers
#define EE 800000   // edges

// Padded GEMM geometry
#define KP 224      // K padded (7 x 32)
#define NP 208      // N padded (13 x 16)
#define XP 224      // xb row pitch (bf16) = 448B
#define AP 232      // LDS A-tile pitch (kRootGemm only)
#define BPP 232     // LDS B-panel pitch (bank-spread for ds_read_b128)
#define RT 128      // rows per kRootGemm tile
#define MSGP 200    // msg row pitch (bf16) -> 400B
#define NSPL 2      // blocks per relation in kMsgP
#define MAXNC 24
#define NPART 128   // partition blocks for the 2-pass sort
#define EPB ((EE + NPART - 1) / NPART)

using bf16x8 = __attribute__((ext_vector_type(8))) short;
using f32x4  = __attribute__((ext_vector_type(4))) float;

// Workspace layout. Fallback path touches only < OFF_CTL.
#define OFF_NORM   0ull          // E f32
#define OFF_SORT   3200000ull    // E i32
#define OFF_CNT    6400000ull    // 4KB ctl (fallback)
#define OFF_XB     6404096ull    // N*XP bf16 = 44.8MB (deg8 20MB aliases transiently)
#define OFF_WT     51204096ull   // R*NP*KP bf16 = 18,636,800
#define OFF_ROOTT  69840896ull   // NP*KP bf16 = 93,184
#define OFF_CTL    69934080ull   // 128KB ctl (big)
#define OFF_POS    70065152ull   // E i32
#define OFF_DSTCNT 73265152ull   // N i32
#define OFF_DSTST  73665152ull   // (N+1) i32 (+pad)
#define OFF_CUR    74065184ull   // N i32
#define OFF_BLKH   74465184ull   // NPART * NC*RR i32 (dynamic) ; msg follows

static __device__ __forceinline__ short f2bf(float v) {
    union { __hip_bfloat16 h; short s; } u;
    u.h = __float2bfloat16(v);
    return u.s;
}

// ---- deg per (dst,rel) + per-dst histogram ----
__global__ void kCount(const int* __restrict__ ei, const int* __restrict__ et,
                       unsigned int* __restrict__ deg8, int* __restrict__ dstCnt, int big) {
    int e = blockIdx.x * 256 + threadIdx.x;
    if (e >= EE) return;
    int d = ei[EE + e];
    int t = et[e];
    int comb = d * RR + t;
    atomicAdd(&deg8[comb >> 2], 1u << ((comb & 3) * 8));
    if (big) atomicAdd(&dstCnt[d], 1);
}

// ---- 3-kernel exclusive scan of dstCnt[N] -> dstStart[N+1] ----
__global__ void kScanBlk(const int* __restrict__ dstCnt, int* __restrict__ dstStart,
                         int* __restrict__ blkSum) {
    __shared__ int s[256];
    int t = threadIdx.x, i = blockIdx.x * 256 + t;
    int v = (i < NN) ? dstCnt[i] : 0;
    s[t] = v;
    __syncthreads();
    #pragma unroll
    for (int off = 1; off < 256; off <<= 1) {
        int x = (t >= off) ? s[t - off] : 0;
        __syncthreads();
        s[t] += x;
        __syncthreads();
    }
    if (i < NN) dstStart[i] = s[t] - v;
    if (t == 255) blkSum[blockIdx.x] = s[255];
}
__global__ void kScanTop(int* __restrict__ blkSum, int nblk) {
    __shared__ int s[512];
    int t = threadIdx.x;
    int v = (t < nblk) ? blkSum[t] : 0;
    s[t] = v;
    __syncthreads();
    #pragma unroll
    for (int off = 1; off < 512; off <<= 1) {
        int x = (t >= off) ? s[t - off] : 0;
        __syncthreads();
        s[t] += x;
        __syncthreads();
    }
    if (t < nblk) blkSum[t] = s[t] - v;
}
__global__ void kScanAdd(const int* __restrict__ dstCnt, int* __restrict__ dstStart,
                         const int* __restrict__ blkSum) {
    int i = blockIdx.x * 256 + threadIdx.x;
    if (i >= NN) return;
    int v = dstStart[i] + blkSum[blockIdx.x];
    dstStart[i] = v;
    if (i == NN - 1) dstStart[NN] = v + dstCnt[i];
}

// ---- chunk boundaries: b[c] = smallest node with dstStart >= c*T ----
__global__ void kChunk(const int* __restrict__ dstStart, int* __restrict__ bS,
                       int* __restrict__ cesS, int NC, int T) {
    int tid = threadIdx.x;
    if (tid > NC) return;
    int v;
    if (tid == NC) v = NN;
    else if (tid == 0) v = 0;
    else {
        int target = tid * T;
        int lo = 0, hi = NN;
        while (lo < hi) {
            int mid = (lo + hi) >> 1;
            if (dstStart[mid] >= target) hi = mid; else lo = mid + 1;
        }
        v = lo;
    }
    bS[tid] = v;
    cesS[tid] = dstStart[v];
}

// ---- PASS 1: per-partition LDS histogram of (chunk,rel) buckets ----
__global__ __launch_bounds__(256) void kHist(const int* __restrict__ ei,
        const int* __restrict__ et, const int* __restrict__ bS,
        int* __restrict__ blockHist, int NC) {
    __shared__ int hist[MAXNC * RR];
    __shared__ int bsh[MAXNC + 1];
    int tid = threadIdx.x, b = blockIdx.x;
    int NB = NC * RR;
    if (tid <= NC) bsh[tid] = bS[tid];
    for (int i = tid; i < NB; i += 256) hist[i] = 0;
    __syncthreads();
    int ebeg = b * EPB, eend = min(EE, ebeg + EPB);
    for (int e = ebeg + tid; e < eend; e += 256) {
        int d = ei[EE + e];
        int t = et[e];
        int c = 0;
        for (int j = 1; j < NC; ++j) if (d >= bsh[j]) c = j;
        atomicAdd(&hist[c * RR + t], 1);
    }
    __syncthreads();
    for (int i = tid; i < NB; i += 256)
        blockHist[(size_t)b * NB + i] = hist[i];
}

// ---- PASS 1b: per-bucket exclusive scan across partitions; totals -> cntB ----
__global__ __launch_bounds__(128) void kScanP(int* __restrict__ blockHist,
                                              int* __restrict__ cntB, int NB) {
    __shared__ int s[NPART];
    int t = threadIdx.x, k = blockIdx.x;
    int v = blockHist[(size_t)t * NB + k];
    s[t] = v;
    __syncthreads();
    #pragma unroll
    for (int off = 1; off < NPART; off <<= 1) {
        int x = (t >= off) ? s[t - off] : 0;
        __syncthreads();
        s[t] += x;
        __syncthreads();
    }
    blockHist[(size_t)t * NB + k] = s[t] - v;
    if (t == NPART - 1) cntB[k] = s[NPART - 1];
}

// ---- bucket scan (nb <= 4800) ----
__global__ void kScanB(const int* __restrict__ cntB, int* __restrict__ relStartB,
                       int* __restrict__ cursorB, int nb) {
    __shared__ int c[MAXNC * RR];
    __shared__ int rs[MAXNC * RR + 1];
    int tid = threadIdx.x;
    for (int i = tid; i < nb; i += 256) c[i] = cntB[i];
    __syncthreads();
    if (tid == 0) {
        int s = 0;
        for (int i = 0; i < nb; ++i) {
            rs[i] = s;
            s += c[i];
        }
        rs[nb] = s;
    }
    __syncthreads();
    for (int i = tid; i <= nb; i += 256) {
        relStartB[i] = rs[i];
        if (i < nb) cursorB[i] = rs[i];
    }
}

// ---- PASS 2: partition scatter with LDS cursors; norm + posDst fused ----
__global__ __launch_bounds__(256) void kPart(const int* __restrict__ ei,
        const int* __restrict__ et, const unsigned int* __restrict__ deg8,
        const int* __restrict__ bS, const int* __restrict__ relStartB,
        const int* __restrict__ blockHist, const int* __restrict__ dstStart,
        int* __restrict__ cur, float* __restrict__ norm, int* __restrict__ sortedE,
        int* __restrict__ posDst, int NC) {
    __shared__ int curL[MAXNC * RR];
    __shared__ int bsh[MAXNC + 1];
    int tid = threadIdx.x, b = blockIdx.x;
    int NB = NC * RR;
    if (tid <= NC) bsh[tid] = bS[tid];
    for (int i = tid; i < NB; i += 256)
        curL[i] = relStartB[i] + blockHist[(size_t)b * NB + i];
    __syncthreads();
    int ebeg = b * EPB, eend = min(EE, ebeg + EPB);
    for (int e = ebeg + tid; e < eend; e += 256) {
        int d = ei[EE + e];
        int t = et[e];
        int comb = d * RR + t;
        unsigned int deg = (deg8[comb >> 2] >> ((comb & 3) * 8)) & 0xffu;
        norm[e] = 1.0f / (float)(deg ? deg : 1u);
        int c = 0;
        for (int j = 1; j < NC; ++j) if (d >= bsh[j]) c = j;
        int pos = atomicAdd(&curL[c * RR + t], 1);
        sortedE[pos] = e;
        posDst[e] = dstStart[d] + atomicAdd(&cur[d], 1);
    }
}

// ---- fallback-only: (chunk, rel) bucket histogram via global atomics ----
__global__ void kCountB(const int* __restrict__ ei, const int* __restrict__ et,
                        const int* __restrict__ bS, int* __restrict__ cntB, int NC) {
    __shared__ int bsh[MAXNC + 1];
    if (threadIdx.x <= NC) bsh[threadIdx.x] = bS[threadIdx.x];
    __syncthreads();
    int e = blockIdx.x * 256 + threadIdx.x;
    if (e >= EE) return;
    int d = ei[EE + e];
    int t = et[e];
    int c = 0;
    for (int j = 1; j < NC; ++j) if (d >= bsh[j]) c = j;
    atomicAdd(&cntB[c * RR + t], 1);
}

// ---- fallback-only: per-edge norm + counting-sort via global cursors ----
__global__ void kNormScatter(const int* __restrict__ ei, const int* __restrict__ et,
                             const unsigned int* __restrict__ deg8, const int* __restrict__ bS,
                             int* __restrict__ cursorB, const int* __restrict__ dstStart,
                             int* __restrict__ cur, float* __restrict__ norm,
                             int* __restrict__ sortedE, int* __restrict__ posDst,
                             int NC, int big) {
    __shared__ int bsh[MAXNC + 1];
    if (threadIdx.x <= NC) bsh[threadIdx.x] = bS[threadIdx.x];
    __syncthreads();
    int e = blockIdx.x * 256 + threadIdx.x;
    if (e >= EE) return;
    int d = ei[EE + e];
    int t = et[e];
    int comb = d * RR + t;
    unsigned int deg = (deg8[comb >> 2] >> ((comb & 3) * 8)) & 0xffu;
    norm[e] = 1.0f / (float)(deg ? deg : 1u);
    int c = 0;
    for (int j = 1; j < NC; ++j) if (d >= bsh[j]) c = j;
    int pos = atomicAdd(&cursorB[c * RR + t], 1);
    sortedE[pos] = e;
    if (big) posDst[e] = dstStart[d] + atomicAdd(&cur[d], 1);
}

// ---- fp32 [N,DD] -> bf16 [N,XP] (cols >= DD zeroed) ----
__global__ void kConvert(const float* __restrict__ x, short* __restrict__ xb, int doRelu) {
    int idx = blockIdx.x * 256 + threadIdx.x;
    if (idx >= NN * XP) return;
    int i = idx / XP, col = idx - i * XP;
    float v = 0.0f;
    if (col < DD) {
        v = x[i * DD + col];
        if (doRelu) v = fmaxf(v, 0.0f);
    }
    xb[idx] = (col < DD) ? f2bf(v) : (short)0;
}

__global__ void kRelu(float* __restrict__ y) {
    int idx = blockIdx.x * 256 + threadIdx.x;
    if (idx < NN * DD) y[idx] = fmaxf(y[idx], 0.0f);
}

// ---- Wt[r][n][k] = sum_b comp[r][b]*bases[b][k][n]; load-once-per-cell ----
__global__ __launch_bounds__(256) void kW(const float* __restrict__ comp,
                                          const float* __restrict__ bases,
                                          short* __restrict__ Wt) {
    int kt = blockIdx.x;                  // 0..6
    int ng = blockIdx.y;                  // 0..25
    int tid = threadIdx.x;
    int k = kt * 32 + (tid & 31);
    int n = ng * 8 + (tid >> 5);
    bool live = (k < DD) && (n < DD);
    float vb[BB];
    #pragma unroll
    for (int b = 0; b < BB; ++b)
        vb[b] = live ? bases[((size_t)b * DD + k) * DD + n] : 0.0f;
    size_t wo = (size_t)n * KP + k;
    for (int r = 0; r < RR; ++r) {
        float a = 0.0f;
        #pragma unroll
        for (int b = 0; b < BB; ++b) a += comp[r * BB + b] * vb[b];
        Wt[(size_t)r * (NP * KP) + wo] = f2bf(a);
    }
}

// ---- rootT[n][k] = root[k][n] ----
__global__ void kRootT(const float* __restrict__ root, short* __restrict__ rootT) {
    int idx = blockIdx.x * 256 + threadIdx.x;
    if (idx >= NP * KP) return;
    int n = idx / KP, k = idx - n * KP;
    rootT[idx] = (n < DD && k < DD) ? f2bf(root[k * DD + n]) : (short)0;
}

// ---- inner GEMM for kRootGemm: 2 M-frags x NF N-frags, kc-double-buffered B ----
template<int F0, int NF>
__device__ __forceinline__ void gemmHalf2(const short* As, const short* bCol,
                                          int arow0, int arow1, int kg,
                                          f32x4* acc0, f32x4* acc1) {
    #pragma unroll
    for (int f = 0; f < NF; ++f) {
        acc0[f] = (f32x4){0.f, 0.f, 0.f, 0.f};
        acc1[f] = (f32x4){0.f, 0.f, 0.f, 0.f};
    }
    bf16x8 bb[2][NF];
    #pragma unroll
    for (int f = 0; f < NF; ++f)
        bb[0][f] = *(const bf16x8*)(bCol + (size_t)(F0 + f) * 16 * KP);
    #pragma unroll
    for (int kc = 0; kc < 7; ++kc) {
        if (kc < 6) {
            #pragma unroll
            for (int f = 0; f < NF; ++f)
                bb[(kc + 1) & 1][f] = *(const bf16x8*)(bCol + (size_t)(F0 + f) * 16 * KP + (kc + 1) * 32);
        }
        bf16x8 a0 = *(const bf16x8*)(&As[arow0 * AP + kc * 32 + kg]);
        bf16x8 a1 = *(const bf16x8*)(&As[arow1 * AP + kc * 32 + kg]);
        #pragma unroll
        for (int f = 0; f < NF; ++f) {
            acc0[f] = __builtin_amdgcn_mfma_f32_16x16x32_bf16(a0, bb[kc & 1][f], acc0[f], 0, 0, 0);
            acc1[f] = __builtin_amdgcn_mfma_f32_16x16x32_bf16(a1, bb[kc & 1][f], acc1[f], 0, 0, 0);
        }
    }
}

// ---- y[i][:] = xb[i][:] @ root + bias  (128 rows/block, 2 M-frags/wave) ----
__global__ __launch_bounds__(256) void kRootGemm(const short* __restrict__ xb,
        const short* __restrict__ rootT, const float* __restrict__ bias,
        float* __restrict__ y) {
    __shared__ short As[RT * AP];
    int i0 = blockIdx.x * RT;
    int tid = threadIdx.x;
    int rowL = tid >> 1, sub = tid & 1;
    int i = i0 + rowL;
    for (int c = sub; c < 28; c += 2) {
        int4 v = make_int4(0, 0, 0, 0);
        if (i < NN) v = *(const int4*)(xb + (size_t)i * XP + c * 8);
        *(int4*)(&As[rowL * AP + c * 8]) = v;
    }
    __syncthreads();
    int lane = tid & 63, wave = tid >> 6;
    int arow0 = wave * 32 + (lane & 15);
    int arow1 = arow0 + 16;
    int kg = (lane >> 4) * 8;
    const short* bCol = rootT + (lane & 15) * KP + kg;
    int colLane = lane & 15;
    int rbase = i0 + wave * 32 + (lane >> 4) * 4;
    {
        f32x4 acc0[7], acc1[7];
        gemmHalf2<0, 7>(As, bCol, arow0, arow1, kg, acc0, acc1);
        #pragma unroll
        for (int f = 0; f < 7; ++f) {
            int col = f * 16 + colLane;
            float bv = bias[col];
            #pragma unroll
            for (int j = 0; j < 4; ++j) {
                int r0 = rbase + j, r1 = rbase + 16 + j;
                if (r0 < NN) y[(size_t)r0 * DD + col] = acc0[f][j] + bv;
                if (r1 < NN) y[(size_t)r1 * DD + col] = acc1[f][j] + bv;
            }
        }
    }
    {
        f32x4 acc0[6], acc1[6];
        gemmHalf2<7, 6>(As, bCol, arow0, arow1, kg, acc0, acc1);
        #pragma unroll
        for (int f = 0; f < 6; ++f) {
            int col = (7 + f) * 16 + colLane;
            if (col < DD) {
                float bv = bias[col];
                #pragma unroll
                for (int j = 0; j < 4; ++j) {
                    int r0 = rbase + j, r1 = rbase + 16 + j;
                    if (r0 < NN) y[(size_t)r0 * DD + col] = acc0[f][j] + bv;
                    if (r1 < NN) y[(size_t)r1 * DD + col] = acc1[f][j] + bv;
                }
            }
        }
    }
}

// ---- relation-resident gather-GEMM: one block per (relation, half).
//      W-panel staged in LDS once; 8 waves loop over 16-edge wave-tiles
//      with one-tile-ahead A-gather prefetch; no barriers in the loop.
//      MODE 0: store msg rows; MODE 1: atomic y ----
template<int MODE>
__global__ __launch_bounds__(512) void kMsgP(const int* __restrict__ ei,
        const short* __restrict__ xb, const short* __restrict__ Wt,
        const int* __restrict__ relStartB, const int* __restrict__ sortedE,
        const float* __restrict__ norm, const int* __restrict__ posDst,
        const int* __restrict__ cesS, float* __restrict__ y,
        short* __restrict__ msg, int c) {
    __shared__ short Bp[NP * BPP];   // 96.5 KB
    int r = blockIdx.x / NSPL;
    int h = blockIdx.x - r * NSPL;
    int relStart = relStartB[c * RR + r];
    int eEnd     = relStartB[c * RR + r + 1];
    int nE = eEnd - relStart;
    if (nE <= 0) return;
    int tid = threadIdx.x;
    // cooperative panel load: Wt[r] is [NP][KP] row-major
    {
        const short* wp = Wt + (size_t)r * (NP * KP);
        for (int idx = tid; idx < NP * (KP / 8); idx += 512) {
            int n = idx / (KP / 8);
            int k8 = idx - n * (KP / 8);
            int4 v = *(const int4*)(wp + (size_t)n * KP + k8 * 8);
            *(int4*)(&Bp[n * BPP + k8 * 8]) = v;
        }
    }
    __syncthreads();
    int lane = tid & 63, wave = tid >> 6;
    int colLane = lane & 15;
    int kg = (lane >> 4) * 8;
    int rbase = (lane >> 4) * 4;
    int nwt = (nE + 15) / 16;
    int ces = (MODE == 0) ? cesS[c] : 0;

    bf16x8 aC[7], aN[7];
    int psC[4], psN[4];
    float nmC[4], nmN[4];

    auto loadTile = [&](int wt, bf16x8* a, int* ps, float* nm) {
        int eBase = relStart + wt * 16;
        int eIdxA = eBase + colLane;
        int eidA = sortedE[min(eIdxA, eEnd - 1)];
        int srcA = ei[eidA];                      // SOURCE node
        const short* aRow = xb + (size_t)srcA * XP;
        #pragma unroll
        for (int kc = 0; kc < 7; ++kc)
            a[kc] = *(const bf16x8*)(aRow + kc * 32 + kg);
        #pragma unroll
        for (int j = 0; j < 4; ++j) {
            int eI = eBase + rbase + j;
            bool v = eI < eEnd;
            int eid = v ? sortedE[eI] : 0;
            nm[j] = v ? norm[eid] : 0.0f;
            if (MODE == 0) ps[j] = v ? (posDst[eid] - ces) : -1;
            else           ps[j] = v ? ei[EE + eid] : -1;
        }
    };

    int wt = h * 8 + wave;
    if (wt < nwt) loadTile(wt, aC, psC, nmC);
    for (; wt < nwt; wt += NSPL * 8) {
        int wtn = wt + NSPL * 8;
        if (wtn < nwt) loadTile(wtn, aN, psN, nmN);
        f32x4 acc[13];
        #pragma unroll
        for (int f = 0; f < 13; ++f) acc[f] = (f32x4){0.f, 0.f, 0.f, 0.f};
        #pragma unroll
        for (int kc = 0; kc < 7; ++kc) {
            bf16x8 bb[13];
            #pragma unroll
            for (int f = 0; f < 13; ++f)
                bb[f] = *(const bf16x8*)(&Bp[(f * 16 + colLane) * BPP + kc * 32 + kg]);
            #pragma unroll
            for (int f = 0; f < 13; ++f)
                acc[f] = __builtin_amdgcn_mfma_f32_16x16x32_bf16(aC[kc], bb[f], acc[f], 0, 0, 0);
        }
        #pragma unroll
        for (int j = 0; j < 4; ++j) {
            int ps = psC[j]; float nm = nmC[j];
            if (ps >= 0) {
                #pragma unroll
                for (int f = 0; f < 13; ++f) {
                    int col = f * 16 + colLane;
                    if (col < DD) {
                        float val = acc[f][j] * nm;
                        if (MODE == 0) msg[(size_t)ps * MSGP + col] = f2bf(val);
                        else           atomicAdd(&y[(size_t)ps * DD + col], val);
                    }
                }
            }
        }
        if (wtn < nwt) {
            #pragma unroll
            for (int kc = 0; kc < 7; ++kc) aC[kc] = aN[kc];
            #pragma unroll
            for (int j = 0; j < 4; ++j) { psC[j] = psN[j]; nmC[j] = nmN[j]; }
        }
    }
}

// ---- grid-stride segmented sum over chunk's node range; y = relu(y + sum(msg)) ----
__global__ __launch_bounds__(256) void kAgg(const short* __restrict__ msg,
        const int* __restrict__ dstStart, const int* __restrict__ bS,
        const int* __restrict__ cesS, float* __restrict__ y, int c) {
    int wv = threadIdx.x >> 6, lane = threadIdx.x & 63;
    int b0 = bS[c], b1 = bS[c + 1];
    int ces = cesS[c];
    int gw = blockIdx.x * 4 + wv;
    int nw = gridDim.x * 4;
    for (int d = b0 + gw; d < b1; d += nw) {
        int s = dstStart[d] - ces, e = dstStart[d + 1] - ces;
        float a0 = 0.f, a1 = 0.f, a2 = 0.f, a3 = 0.f;
        if (lane < 50) {
            for (int j = s; j < e; ++j) {
                int2 v = *(const int2*)(msg + (size_t)j * MSGP + lane * 4);
                unsigned u0 = (unsigned)v.x, u1 = (unsigned)v.y;
                a0 += __uint_as_float(u0 << 16);
                a1 += __uint_as_float(u0 & 0xffff0000u);
                a2 += __uint_as_float(u1 << 16);
                a3 += __uint_as_float(u1 & 0xffff0000u);
            }
            int colBase = lane * 4;
            float4 rv = *(const float4*)(y + (size_t)d * DD + colBase);
            float4 o;
            o.x = fmaxf(rv.x + a0, 0.f);
            o.y = fmaxf(rv.y + a1, 0.f);
            o.z = fmaxf(rv.z + a2, 0.f);
            o.w = fmaxf(rv.w + a3, 0.f);
            *(float4*)(y + (size_t)d * DD + colBase) = o;
        }
    }
}

extern "C" void kernel_launch(void* const* d_in, const int* in_sizes, int n_in,
                              void* d_out, int out_size, void* d_ws, size_t ws_size,
                              hipStream_t stream) {
    (void)in_sizes; (void)n_in; (void)out_size;
    const int*   ei    = (const int*)d_in[0];
    const int*   et    = (const int*)d_in[1];
    const float* emb   = (const float*)d_in[2];
    const float* comp  = (const float*)d_in[3];
    const float* bases = (const float*)d_in[4];
    const float* root  = (const float*)d_in[5];
    const float* bias  = (const float*)d_in[6];
    float* y = (float*)d_out;
    char* ws = (char*)d_ws;
    float* norm    = (float*)(ws + OFF_NORM);
    int*   sortedE = (int*)(ws + OFF_SORT);
    short* xb      = (short*)(ws + OFF_XB);
    short* Wt      = (short*)(ws + OFF_WT);
    short* rootT   = (short*)(ws + OFF_ROOTT);
    int*   posDst  = (int*)(ws + OFF_POS);
    int*   dstCnt  = (int*)(ws + OFF_DSTCNT);
    int*   dstStart= (int*)(ws + OFF_DSTST);
    int*   cur     = (int*)(ws + OFF_CUR);
    int*   blockHist = (int*)(ws + OFF_BLKH);
    unsigned int* deg8 = (unsigned int*)(ws + OFF_XB);  // transient alias

    // choose chunk count from available workspace (pure function of ws_size)
    int NC = 0;
    long long T = EE;
    unsigned long long msgOff = 0;
    for (int cc = 1; cc <= MAXNC; ++cc) {
        long long t = (EE + cc - 1) / cc;
        unsigned long long mo = OFF_BLKH + (unsigned long long)NPART * cc * RR * 4;
        unsigned long long need = mo + (unsigned long long)(t + 64) * (MSGP * 2);
        if ((unsigned long long)ws_size >= need) { NC = cc; T = t; msgOff = mo; break; }
    }
    int big = (NC > 0) ? 1 : 0;
    if (!big) { NC = 1; T = EE; msgOff = OFF_BLKH; }
    short* msg = (short*)(ws + msgOff);

    int *cntB, *relStartB, *cursorB, *bS, *cesS, *blkSum;
    if (big) {
        int* ctl = (int*)(ws + OFF_CTL);
        cntB = ctl; relStartB = ctl + 4864; cursorB = ctl + 9728;
        bS = ctl + 19456; cesS = ctl + 19520; blkSum = ctl + 19584;
    } else {
        int* ctl = (int*)(ws + OFF_CNT);
        cntB = ctl; relStartB = ctl + 256; cursorB = ctl + 512;
        bS = ctl + 976; cesS = ctl + 992; blkSum = ctl + 1000;
    }

    const int NBLK = (NN + 255) / 256;  // 391

    hipMemsetAsync(deg8, 0, (size_t)NN * RR, stream);
    if (big) {
        hipMemsetAsync(dstCnt, 0, (size_t)NN * 4, stream);
        hipMemsetAsync(cur, 0, (size_t)NN * 4, stream);
    } else {
        hipMemsetAsync((void*)cntB, 0, 4096, stream);
    }

    kCount<<<(EE + 255) / 256, 256, 0, stream>>>(ei, et, deg8, dstCnt, big);
    if (big) {
        kScanBlk<<<NBLK, 256, 0, stream>>>(dstCnt, dstStart, blkSum);
        kScanTop<<<1, 512, 0, stream>>>(blkSum, NBLK);
        kScanAdd<<<NBLK, 256, 0, stream>>>(dstCnt, dstStart, blkSum);
        kChunk<<<1, 64, 0, stream>>>(dstStart, bS, cesS, NC, (int)T);
        // contention-free 2-pass counting sort
        kHist<<<NPART, 256, 0, stream>>>(ei, et, bS, blockHist, NC);
        kScanP<<<NC * RR, NPART, 0, stream>>>(blockHist, cntB, NC * RR);
        kScanB<<<1, 256, 0, stream>>>(cntB, relStartB, cursorB, NC * RR);
        kPart<<<NPART, 256, 0, stream>>>(ei, et, deg8, bS, relStartB, blockHist,
                                         dstStart, cur, norm, sortedE, posDst, NC);
    } else {
        kCountB<<<(EE + 255) / 256, 256, 0, stream>>>(ei, et, bS, cntB, NC);
        kScanB<<<1, 256, 0, stream>>>(cntB, relStartB, cursorB, NC * RR);
        kNormScatter<<<(EE + 255) / 256, 256, 0, stream>>>(ei, et, deg8, bS, cursorB,
                                                           dstStart, cur, norm, sortedE,
                                                           posDst, NC, big);
    }
    kConvert<<<(NN * XP + 255) / 256, 256, 0, stream>>>(emb, xb, 0);

    for (int l = 0; l < LL; ++l) {
        kW<<<dim3(7, 26), 256, 0, stream>>>(comp + l * RR * BB,
                                            bases + (size_t)l * BB * DD * DD, Wt);
        kRootT<<<(NP * KP + 255) / 256, 256, 0, stream>>>(root + l * DD * DD, rootT);
        kRootGemm<<<(NN + RT - 1) / RT, 256, 0, stream>>>(xb, rootT, bias + l * DD, y);
        if (big) {
            for (int c = 0; c < NC; ++c) {
                kMsgP<0><<<RR * NSPL, 512, 0, stream>>>(ei, xb, Wt, relStartB, sortedE,
                                                        norm, posDst, cesS, y, msg, c);
                kAgg<<<2048, 256, 0, stream>>>(msg, dstStart, bS, cesS, y, c);
            }
            if (l == 0)
                kConvert<<<(NN * XP + 255) / 256, 256, 0, stream>>>(y, xb, 0);
        } else {
            kMsgP<1><<<RR * NSPL, 512, 0, stream>>>(ei, xb, Wt, relStartB, sortedE,
                                                    norm, posDst, cesS, y, msg, 0);
            if (l == 0) kConvert<<<(NN * XP + 255) / 256, 256, 0, stream>>>(y, xb, 1);
            else        kRelu<<<(NN * DD + 255) / 256, 256, 0, stream>>>(y);
        }
    }
}

// Round 10
// 1262.656 us; speedup vs baseline: 1.2797x; 1.0247x over previous
//
#include <hip/hip_runtime.h>
#include <hip/hip_bf16.h>
#include <stdint.h>

// Problem constants
#define NN 100000   // nodes
#define RR 200      // relations
#define DD 200      // dim
#define BB 30       // bases
#define LL 2        // layers
#define EE 800000   // edges

// Padded GEMM geometry
#define KP 224      // K padded (7 x 32)
#define NP 208      // N padded (13 x 16)
#define XP 224      // xb row pitch (bf16) = 448B
#define AP 232      // LDS A-tile pitch (kRootGemm only)
#define BPP 232     // LDS B-panel pitch (bank-spread for ds_read_b128)
#define RT 128      // rows per kRootGemm tile
#define MSGP 200    // msg row pitch (bf16) -> 400B
#define NSPL 2      // blocks per relation in kMsgP
#define MAXNC 24
#define NPART 128   // partition blocks for the 2-pass sort
#define EPB ((EE + NPART - 1) / NPART)

using bf16x8 = __attribute__((ext_vector_type(8))) short;
using f32x4  = __attribute__((ext_vector_type(4))) float;

// Workspace layout. Fallback path touches only < OFF_CTL.
#define OFF_NORM   0ull          // E f32
#define OFF_SORT   3200000ull    // E i32
#define OFF_CNT    6400000ull    // 4KB ctl (fallback)
#define OFF_XB     6404096ull    // N*XP bf16 = 44.8MB (deg8 20MB aliases transiently)
#define OFF_WT     51204096ull   // R*NP*KP bf16 = 18,636,800
#define OFF_ROOTT  69840896ull   // NP*KP bf16 = 93,184
#define OFF_CTL    69934080ull   // 128KB ctl (big)
#define OFF_POS    70065152ull   // E i32
#define OFF_DSTCNT 73265152ull   // N i32
#define OFF_DSTST  73665152ull   // (N+1) i32 (+pad)
#define OFF_CUR    74065184ull   // N i32
#define OFF_BLKH   74465184ull   // NPART * NC*RR i32 (dynamic) ; msg follows

static __device__ __forceinline__ short f2bf(float v) {
    union { __hip_bfloat16 h; short s; } u;
    u.h = __float2bfloat16(v);
    return u.s;
}

// ---- deg per (dst,rel) + per-dst histogram ----
__global__ void kCount(const int* __restrict__ ei, const int* __restrict__ et,
                       unsigned int* __restrict__ deg8, int* __restrict__ dstCnt, int big) {
    int e = blockIdx.x * 256 + threadIdx.x;
    if (e >= EE) return;
    int d = ei[EE + e];
    int t = et[e];
    int comb = d * RR + t;
    atomicAdd(&deg8[comb >> 2], 1u << ((comb & 3) * 8));
    if (big) atomicAdd(&dstCnt[d], 1);
}

// ---- 3-kernel exclusive scan of dstCnt[N] -> dstStart[N+1] ----
__global__ void kScanBlk(const int* __restrict__ dstCnt, int* __restrict__ dstStart,
                         int* __restrict__ blkSum) {
    __shared__ int s[256];
    int t = threadIdx.x, i = blockIdx.x * 256 + t;
    int v = (i < NN) ? dstCnt[i] : 0;
    s[t] = v;
    __syncthreads();
    #pragma unroll
    for (int off = 1; off < 256; off <<= 1) {
        int x = (t >= off) ? s[t - off] : 0;
        __syncthreads();
        s[t] += x;
        __syncthreads();
    }
    if (i < NN) dstStart[i] = s[t] - v;
    if (t == 255) blkSum[blockIdx.x] = s[255];
}
__global__ void kScanTop(int* __restrict__ blkSum, int nblk) {
    __shared__ int s[512];
    int t = threadIdx.x;
    int v = (t < nblk) ? blkSum[t] : 0;
    s[t] = v;
    __syncthreads();
    #pragma unroll
    for (int off = 1; off < 512; off <<= 1) {
        int x = (t >= off) ? s[t - off] : 0;
        __syncthreads();
        s[t] += x;
        __syncthreads();
    }
    if (t < nblk) blkSum[t] = s[t] - v;
}
__global__ void kScanAdd(const int* __restrict__ dstCnt, int* __restrict__ dstStart,
                         const int* __restrict__ blkSum) {
    int i = blockIdx.x * 256 + threadIdx.x;
    if (i >= NN) return;
    int v = dstStart[i] + blkSum[blockIdx.x];
    dstStart[i] = v;
    if (i == NN - 1) dstStart[NN] = v + dstCnt[i];
}

// ---- chunk boundaries: b[c] = smallest node with dstStart >= c*T ----
__global__ void kChunk(const int* __restrict__ dstStart, int* __restrict__ bS,
                       int* __restrict__ cesS, int NC, int T) {
    int tid = threadIdx.x;
    if (tid > NC) return;
    int v;
    if (tid == NC) v = NN;
    else if (tid == 0) v = 0;
    else {
        int target = tid * T;
        int lo = 0, hi = NN;
        while (lo < hi) {
            int mid = (lo + hi) >> 1;
            if (dstStart[mid] >= target) hi = mid; else lo = mid + 1;
        }
        v = lo;
    }
    bS[tid] = v;
    cesS[tid] = dstStart[v];
}

// ---- PASS 1: per-partition LDS histogram of (chunk,rel) buckets ----
__global__ __launch_bounds__(256) void kHist(const int* __restrict__ ei,
        const int* __restrict__ et, const int* __restrict__ bS,
        int* __restrict__ blockHist, int NC) {
    __shared__ int hist[MAXNC * RR];
    __shared__ int bsh[MAXNC + 1];
    int tid = threadIdx.x, b = blockIdx.x;
    int NB = NC * RR;
    if (tid <= NC) bsh[tid] = bS[tid];
    for (int i = tid; i < NB; i += 256) hist[i] = 0;
    __syncthreads();
    int ebeg = b * EPB, eend = min(EE, ebeg + EPB);
    for (int e = ebeg + tid; e < eend; e += 256) {
        int d = ei[EE + e];
        int t = et[e];
        int c = 0;
        for (int j = 1; j < NC; ++j) if (d >= bsh[j]) c = j;
        atomicAdd(&hist[c * RR + t], 1);
    }
    __syncthreads();
    for (int i = tid; i < NB; i += 256)
        blockHist[(size_t)b * NB + i] = hist[i];
}

// ---- PASS 1b: per-bucket exclusive scan across partitions; totals -> cntB ----
__global__ __launch_bounds__(128) void kScanP(int* __restrict__ blockHist,
                                              int* __restrict__ cntB, int NB) {
    __shared__ int s[NPART];
    int t = threadIdx.x, k = blockIdx.x;
    int v = blockHist[(size_t)t * NB + k];
    s[t] = v;
    __syncthreads();
    #pragma unroll
    for (int off = 1; off < NPART; off <<= 1) {
        int x = (t >= off) ? s[t - off] : 0;
        __syncthreads();
        s[t] += x;
        __syncthreads();
    }
    blockHist[(size_t)t * NB + k] = s[t] - v;
    if (t == NPART - 1) cntB[k] = s[NPART - 1];
}

// ---- bucket scan (nb <= 4800) ----
__global__ void kScanB(const int* __restrict__ cntB, int* __restrict__ relStartB,
                       int* __restrict__ cursorB, int nb) {
    __shared__ int c[MAXNC * RR];
    __shared__ int rs[MAXNC * RR + 1];
    int tid = threadIdx.x;
    for (int i = tid; i < nb; i += 256) c[i] = cntB[i];
    __syncthreads();
    if (tid == 0) {
        int s = 0;
        for (int i = 0; i < nb; ++i) {
            rs[i] = s;
            s += c[i];
        }
        rs[nb] = s;
    }
    __syncthreads();
    for (int i = tid; i <= nb; i += 256) {
        relStartB[i] = rs[i];
        if (i < nb) cursorB[i] = rs[i];
    }
}

// ---- PASS 2: partition scatter with LDS cursors; norm + posDst fused ----
__global__ __launch_bounds__(256) void kPart(const int* __restrict__ ei,
        const int* __restrict__ et, const unsigned int* __restrict__ deg8,
        const int* __restrict__ bS, const int* __restrict__ relStartB,
        const int* __restrict__ blockHist, const int* __restrict__ dstStart,
        int* __restrict__ cur, float* __restrict__ norm, int* __restrict__ sortedE,
        int* __restrict__ posDst, int NC) {
    __shared__ int curL[MAXNC * RR];
    __shared__ int bsh[MAXNC + 1];
    int tid = threadIdx.x, b = blockIdx.x;
    int NB = NC * RR;
    if (tid <= NC) bsh[tid] = bS[tid];
    for (int i = tid; i < NB; i += 256)
        curL[i] = relStartB[i] + blockHist[(size_t)b * NB + i];
    __syncthreads();
    int ebeg = b * EPB, eend = min(EE, ebeg + EPB);
    for (int e = ebeg + tid; e < eend; e += 256) {
        int d = ei[EE + e];
        int t = et[e];
        int comb = d * RR + t;
        unsigned int deg = (deg8[comb >> 2] >> ((comb & 3) * 8)) & 0xffu;
        norm[e] = 1.0f / (float)(deg ? deg : 1u);
        int c = 0;
        for (int j = 1; j < NC; ++j) if (d >= bsh[j]) c = j;
        int pos = atomicAdd(&curL[c * RR + t], 1);
        sortedE[pos] = e;
        posDst[e] = dstStart[d] + atomicAdd(&cur[d], 1);
    }
}

// ---- fallback-only: (chunk, rel) bucket histogram via global atomics ----
__global__ void kCountB(const int* __restrict__ ei, const int* __restrict__ et,
                        const int* __restrict__ bS, int* __restrict__ cntB, int NC) {
    __shared__ int bsh[MAXNC + 1];
    if (threadIdx.x <= NC) bsh[threadIdx.x] = bS[threadIdx.x];
    __syncthreads();
    int e = blockIdx.x * 256 + threadIdx.x;
    if (e >= EE) return;
    int d = ei[EE + e];
    int t = et[e];
    int c = 0;
    for (int j = 1; j < NC; ++j) if (d >= bsh[j]) c = j;
    atomicAdd(&cntB[c * RR + t], 1);
}

// ---- fallback-only: per-edge norm + counting-sort via global cursors ----
__global__ void kNormScatter(const int* __restrict__ ei, const int* __restrict__ et,
                             const unsigned int* __restrict__ deg8, const int* __restrict__ bS,
                             int* __restrict__ cursorB, const int* __restrict__ dstStart,
                             int* __restrict__ cur, float* __restrict__ norm,
                             int* __restrict__ sortedE, int* __restrict__ posDst,
                             int NC, int big) {
    __shared__ int bsh[MAXNC + 1];
    if (threadIdx.x <= NC) bsh[threadIdx.x] = bS[threadIdx.x];
    __syncthreads();
    int e = blockIdx.x * 256 + threadIdx.x;
    if (e >= EE) return;
    int d = ei[EE + e];
    int t = et[e];
    int comb = d * RR + t;
    unsigned int deg = (deg8[comb >> 2] >> ((comb & 3) * 8)) & 0xffu;
    norm[e] = 1.0f / (float)(deg ? deg : 1u);
    int c = 0;
    for (int j = 1; j < NC; ++j) if (d >= bsh[j]) c = j;
    int pos = atomicAdd(&cursorB[c * RR + t], 1);
    sortedE[pos] = e;
    if (big) posDst[e] = dstStart[d] + atomicAdd(&cur[d], 1);
}

// ---- fp32 [N,DD] -> bf16 [N,XP] (cols >= DD zeroed) ----
__global__ void kConvert(const float* __restrict__ x, short* __restrict__ xb, int doRelu) {
    int idx = blockIdx.x * 256 + threadIdx.x;
    if (idx >= NN * XP) return;
    int i = idx / XP, col = idx - i * XP;
    float v = 0.0f;
    if (col < DD) {
        v = x[i * DD + col];
        if (doRelu) v = fmaxf(v, 0.0f);
    }
    xb[idx] = (col < DD) ? f2bf(v) : (short)0;
}

__global__ void kRelu(float* __restrict__ y) {
    int idx = blockIdx.x * 256 + threadIdx.x;
    if (idx < NN * DD) y[idx] = fmaxf(y[idx], 0.0f);
}

// ---- Wt[r][n][k] = sum_b comp[r][b]*bases[b][k][n]; load-once-per-cell ----
__global__ __launch_bounds__(256) void kW(const float* __restrict__ comp,
                                          const float* __restrict__ bases,
                                          short* __restrict__ Wt) {
    int kt = blockIdx.x;                  // 0..6
    int ng = blockIdx.y;                  // 0..25
    int tid = threadIdx.x;
    int k = kt * 32 + (tid & 31);
    int n = ng * 8 + (tid >> 5);
    bool live = (k < DD) && (n < DD);
    float vb[BB];
    #pragma unroll
    for (int b = 0; b < BB; ++b)
        vb[b] = live ? bases[((size_t)b * DD + k) * DD + n] : 0.0f;
    size_t wo = (size_t)n * KP + k;
    for (int r = 0; r < RR; ++r) {
        float a = 0.0f;
        #pragma unroll
        for (int b = 0; b < BB; ++b) a += comp[r * BB + b] * vb[b];
        Wt[(size_t)r * (NP * KP) + wo] = f2bf(a);
    }
}

// ---- rootT[n][k] = root[k][n] ----
__global__ void kRootT(const float* __restrict__ root, short* __restrict__ rootT) {
    int idx = blockIdx.x * 256 + threadIdx.x;
    if (idx >= NP * KP) return;
    int n = idx / KP, k = idx - n * KP;
    rootT[idx] = (n < DD && k < DD) ? f2bf(root[k * DD + n]) : (short)0;
}

// ---- inner GEMM for kRootGemm: 2 M-frags x NF N-frags, kc-double-buffered B ----
template<int F0, int NF>
__device__ __forceinline__ void gemmHalf2(const short* As, const short* bCol,
                                          int arow0, int arow1, int kg,
                                          f32x4* acc0, f32x4* acc1) {
    #pragma unroll
    for (int f = 0; f < NF; ++f) {
        acc0[f] = (f32x4){0.f, 0.f, 0.f, 0.f};
        acc1[f] = (f32x4){0.f, 0.f, 0.f, 0.f};
    }
    bf16x8 bb[2][NF];
    #pragma unroll
    for (int f = 0; f < NF; ++f)
        bb[0][f] = *(const bf16x8*)(bCol + (size_t)(F0 + f) * 16 * KP);
    #pragma unroll
    for (int kc = 0; kc < 7; ++kc) {
        if (kc < 6) {
            #pragma unroll
            for (int f = 0; f < NF; ++f)
                bb[(kc + 1) & 1][f] = *(const bf16x8*)(bCol + (size_t)(F0 + f) * 16 * KP + (kc + 1) * 32);
        }
        bf16x8 a0 = *(const bf16x8*)(&As[arow0 * AP + kc * 32 + kg]);
        bf16x8 a1 = *(const bf16x8*)(&As[arow1 * AP + kc * 32 + kg]);
        #pragma unroll
        for (int f = 0; f < NF; ++f) {
            acc0[f] = __builtin_amdgcn_mfma_f32_16x16x32_bf16(a0, bb[kc & 1][f], acc0[f], 0, 0, 0);
            acc1[f] = __builtin_amdgcn_mfma_f32_16x16x32_bf16(a1, bb[kc & 1][f], acc1[f], 0, 0, 0);
        }
    }
}

// ---- y[i][:] = xb[i][:] @ root + bias  (128 rows/block, 2 M-frags/wave) ----
__global__ __launch_bounds__(256) void kRootGemm(const short* __restrict__ xb,
        const short* __restrict__ rootT, const float* __restrict__ bias,
        float* __restrict__ y) {
    __shared__ short As[RT * AP];
    int i0 = blockIdx.x * RT;
    int tid = threadIdx.x;
    int rowL = tid >> 1, sub = tid & 1;
    int i = i0 + rowL;
    for (int c = sub; c < 28; c += 2) {
        int4 v = make_int4(0, 0, 0, 0);
        if (i < NN) v = *(const int4*)(xb + (size_t)i * XP + c * 8);
        *(int4*)(&As[rowL * AP + c * 8]) = v;
    }
    __syncthreads();
    int lane = tid & 63, wave = tid >> 6;
    int arow0 = wave * 32 + (lane & 15);
    int arow1 = arow0 + 16;
    int kg = (lane >> 4) * 8;
    const short* bCol = rootT + (lane & 15) * KP + kg;
    int colLane = lane & 15;
    int rbase = i0 + wave * 32 + (lane >> 4) * 4;
    {
        f32x4 acc0[7], acc1[7];
        gemmHalf2<0, 7>(As, bCol, arow0, arow1, kg, acc0, acc1);
        #pragma unroll
        for (int f = 0; f < 7; ++f) {
            int col = f * 16 + colLane;
            float bv = bias[col];
            #pragma unroll
            for (int j = 0; j < 4; ++j) {
                int r0 = rbase + j, r1 = rbase + 16 + j;
                if (r0 < NN) y[(size_t)r0 * DD + col] = acc0[f][j] + bv;
                if (r1 < NN) y[(size_t)r1 * DD + col] = acc1[f][j] + bv;
            }
        }
    }
    {
        f32x4 acc0[6], acc1[6];
        gemmHalf2<7, 6>(As, bCol, arow0, arow1, kg, acc0, acc1);
        #pragma unroll
        for (int f = 0; f < 6; ++f) {
            int col = (7 + f) * 16 + colLane;
            if (col < DD) {
                float bv = bias[col];
                #pragma unroll
                for (int j = 0; j < 4; ++j) {
                    int r0 = rbase + j, r1 = rbase + 16 + j;
                    if (r0 < NN) y[(size_t)r0 * DD + col] = acc0[f][j] + bv;
                    if (r1 < NN) y[(size_t)r1 * DD + col] = acc1[f][j] + bv;
                }
            }
        }
    }
}

// ---- relation-resident gather-GEMM: one block per (relation, half).
//      W-panel in LDS; 8 waves loop over 32-edge wave-tiles (2 M-frags/wave,
//      each LDS B-read feeds 2 MFMAs), one-tile-ahead A-gather prefetch.
//      MODE 0: store msg rows; MODE 1: atomic y ----
template<int MODE>
__global__ __launch_bounds__(512) void kMsgP(const int* __restrict__ ei,
        const short* __restrict__ xb, const short* __restrict__ Wt,
        const int* __restrict__ relStartB, const int* __restrict__ sortedE,
        const float* __restrict__ norm, const int* __restrict__ posDst,
        const int* __restrict__ cesS, float* __restrict__ y,
        short* __restrict__ msg, int c) {
    __shared__ short Bp[NP * BPP];   // 96.5 KB
    int r = blockIdx.x / NSPL;
    int h = blockIdx.x - r * NSPL;
    int relStart = relStartB[c * RR + r];
    int eEnd     = relStartB[c * RR + r + 1];
    int nE = eEnd - relStart;
    if (nE <= 0) return;
    int tid = threadIdx.x;
    // cooperative panel load: Wt[r] is [NP][KP] row-major
    {
        const short* wp = Wt + (size_t)r * (NP * KP);
        for (int idx = tid; idx < NP * (KP / 8); idx += 512) {
            int n = idx / (KP / 8);
            int k8 = idx - n * (KP / 8);
            int4 v = *(const int4*)(wp + (size_t)n * KP + k8 * 8);
            *(int4*)(&Bp[n * BPP + k8 * 8]) = v;
        }
    }
    __syncthreads();
    int lane = tid & 63, wave = tid >> 6;
    int colLane = lane & 15;
    int kg = (lane >> 4) * 8;
    int rbase = (lane >> 4) * 4;
    int nwt = (nE + 31) / 32;            // 32-edge wave-tiles
    int ces = (MODE == 0) ? cesS[c] : 0;

    bf16x8 aC[2][7], aN[2][7];
    int psC[2][4], psN[2][4];
    float nmC[2][4], nmN[2][4];

    auto loadTile = [&](int wt, bf16x8 (*a)[7], int (*ps)[4], float (*nm)[4]) {
        int eBase = relStart + wt * 32;
        #pragma unroll
        for (int m = 0; m < 2; ++m) {
            int eIdxA = eBase + m * 16 + colLane;
            int eidA = sortedE[min(eIdxA, eEnd - 1)];
            int srcA = ei[eidA];                  // SOURCE node
            const short* aRow = xb + (size_t)srcA * XP;
            #pragma unroll
            for (int kc = 0; kc < 7; ++kc)
                a[m][kc] = *(const bf16x8*)(aRow + kc * 32 + kg);
            #pragma unroll
            for (int j = 0; j < 4; ++j) {
                int eI = eBase + m * 16 + rbase + j;
                bool v = eI < eEnd;
                int eid = v ? sortedE[eI] : 0;
                nm[m][j] = v ? norm[eid] : 0.0f;
                if (MODE == 0) ps[m][j] = v ? (posDst[eid] - ces) : -1;
                else           ps[m][j] = v ? ei[EE + eid] : -1;
            }
        }
    };

    int wt = h * 8 + wave;
    if (wt < nwt) loadTile(wt, aC, psC, nmC);
    for (; wt < nwt; wt += NSPL * 8) {
        int wtn = wt + NSPL * 8;
        if (wtn < nwt) loadTile(wtn, aN, psN, nmN);
        // pass 1: f = 0..6
        {
            f32x4 acc0[7], acc1[7];
            #pragma unroll
            for (int f = 0; f < 7; ++f) {
                acc0[f] = (f32x4){0.f, 0.f, 0.f, 0.f};
                acc1[f] = (f32x4){0.f, 0.f, 0.f, 0.f};
            }
            #pragma unroll
            for (int kc = 0; kc < 7; ++kc) {
                bf16x8 bb[7];
                #pragma unroll
                for (int f = 0; f < 7; ++f)
                    bb[f] = *(const bf16x8*)(&Bp[(f * 16 + colLane) * BPP + kc * 32 + kg]);
                #pragma unroll
                for (int f = 0; f < 7; ++f) {
                    acc0[f] = __builtin_amdgcn_mfma_f32_16x16x32_bf16(aC[0][kc], bb[f], acc0[f], 0, 0, 0);
                    acc1[f] = __builtin_amdgcn_mfma_f32_16x16x32_bf16(aC[1][kc], bb[f], acc1[f], 0, 0, 0);
                }
            }
            #pragma unroll
            for (int m = 0; m < 2; ++m) {
                #pragma unroll
                for (int j = 0; j < 4; ++j) {
                    int ps = psC[m][j]; float nm = nmC[m][j];
                    if (ps >= 0) {
                        #pragma unroll
                        for (int f = 0; f < 7; ++f) {
                            int col = f * 16 + colLane;
                            float val = (m ? acc1[f][j] : acc0[f][j]) * nm;
                            if (MODE == 0) msg[(size_t)ps * MSGP + col] = f2bf(val);
                            else           atomicAdd(&y[(size_t)ps * DD + col], val);
                        }
                    }
                }
            }
        }
        // pass 2: f = 7..12
        {
            f32x4 acc0[6], acc1[6];
            #pragma unroll
            for (int f = 0; f < 6; ++f) {
                acc0[f] = (f32x4){0.f, 0.f, 0.f, 0.f};
                acc1[f] = (f32x4){0.f, 0.f, 0.f, 0.f};
            }
            #pragma unroll
            for (int kc = 0; kc < 7; ++kc) {
                bf16x8 bb[6];
                #pragma unroll
                for (int f = 0; f < 6; ++f)
                    bb[f] = *(const bf16x8*)(&Bp[((7 + f) * 16 + colLane) * BPP + kc * 32 + kg]);
                #pragma unroll
                for (int f = 0; f < 6; ++f) {
                    acc0[f] = __builtin_amdgcn_mfma_f32_16x16x32_bf16(aC[0][kc], bb[f], acc0[f], 0, 0, 0);
                    acc1[f] = __builtin_amdgcn_mfma_f32_16x16x32_bf16(aC[1][kc], bb[f], acc1[f], 0, 0, 0);
                }
            }
            #pragma unroll
            for (int m = 0; m < 2; ++m) {
                #pragma unroll
                for (int j = 0; j < 4; ++j) {
                    int ps = psC[m][j]; float nm = nmC[m][j];
                    if (ps >= 0) {
                        #pragma unroll
                        for (int f = 0; f < 6; ++f) {
                            int col = (7 + f) * 16 + colLane;
                            if (col < DD) {
                                float val = (m ? acc1[f][j] : acc0[f][j]) * nm;
                                if (MODE == 0) msg[(size_t)ps * MSGP + col] = f2bf(val);
                                else           atomicAdd(&y[(size_t)ps * DD + col], val);
                            }
                        }
                    }
                }
            }
        }
        if (wtn < nwt) {
            #pragma unroll
            for (int m = 0; m < 2; ++m) {
                #pragma unroll
                for (int kc = 0; kc < 7; ++kc) aC[m][kc] = aN[m][kc];
                #pragma unroll
                for (int j = 0; j < 4; ++j) { psC[m][j] = psN[m][j]; nmC[m][j] = nmN[m][j]; }
            }
        }
    }
}

// ---- grid-stride segmented sum over chunk's node range; y = relu(y + sum(msg)) ----
__global__ __launch_bounds__(256) void kAgg(const short* __restrict__ msg,
        const int* __restrict__ dstStart, const int* __restrict__ bS,
        const int* __restrict__ cesS, float* __restrict__ y, int c) {
    int wv = threadIdx.x >> 6, lane = threadIdx.x & 63;
    int b0 = bS[c], b1 = bS[c + 1];
    int ces = cesS[c];
    int gw = blockIdx.x * 4 + wv;
    int nw = gridDim.x * 4;
    for (int d = b0 + gw; d < b1; d += nw) {
        int s = dstStart[d] - ces, e = dstStart[d + 1] - ces;
        float a0 = 0.f, a1 = 0.f, a2 = 0.f, a3 = 0.f;
        if (lane < 50) {
            for (int j = s; j < e; ++j) {
                int2 v = *(const int2*)(msg + (size_t)j * MSGP + lane * 4);
                unsigned u0 = (unsigned)v.x, u1 = (unsigned)v.y;
                a0 += __uint_as_float(u0 << 16);
                a1 += __uint_as_float(u0 & 0xffff0000u);
                a2 += __uint_as_float(u1 << 16);
                a3 += __uint_as_float(u1 & 0xffff0000u);
            }
            int colBase = lane * 4;
            float4 rv = *(const float4*)(y + (size_t)d * DD + colBase);
            float4 o;
            o.x = fmaxf(rv.x + a0, 0.f);
            o.y = fmaxf(rv.y + a1, 0.f);
            o.z = fmaxf(rv.z + a2, 0.f);
            o.w = fmaxf(rv.w + a3, 0.f);
            *(float4*)(y + (size_t)d * DD + colBase) = o;
        }
    }
}

extern "C" void kernel_launch(void* const* d_in, const int* in_sizes, int n_in,
                              void* d_out, int out_size, void* d_ws, size_t ws_size,
                              hipStream_t stream) {
    (void)in_sizes; (void)n_in; (void)out_size;
    const int*   ei    = (const int*)d_in[0];
    const int*   et    = (const int*)d_in[1];
    const float* emb   = (const float*)d_in[2];
    const float* comp  = (const float*)d_in[3];
    const float* bases = (const float*)d_in[4];
    const float* root  = (const float*)d_in[5];
    const float* bias  = (const float*)d_in[6];
    float* y = (float*)d_out;
    char* ws = (char*)d_ws;
    float* norm    = (float*)(ws + OFF_NORM);
    int*   sortedE = (int*)(ws + OFF_SORT);
    short* xb      = (short*)(ws + OFF_XB);
    short* Wt      = (short*)(ws + OFF_WT);
    short* rootT   = (short*)(ws + OFF_ROOTT);
    int*   posDst  = (int*)(ws + OFF_POS);
    int*   dstCnt  = (int*)(ws + OFF_DSTCNT);
    int*   dstStart= (int*)(ws + OFF_DSTST);
    int*   cur     = (int*)(ws + OFF_CUR);
    int*   blockHist = (int*)(ws + OFF_BLKH);
    unsigned int* deg8 = (unsigned int*)(ws + OFF_XB);  // transient alias

    // choose chunk count from available workspace (pure function of ws_size)
    int NC = 0;
    long long T = EE;
    unsigned long long msgOff = 0;
    for (int cc = 1; cc <= MAXNC; ++cc) {
        long long t = (EE + cc - 1) / cc;
        unsigned long long mo = OFF_BLKH + (unsigned long long)NPART * cc * RR * 4;
        unsigned long long need = mo + (unsigned long long)(t + 64) * (MSGP * 2);
        if ((unsigned long long)ws_size >= need) { NC = cc; T = t; msgOff = mo; break; }
    }
    int big = (NC > 0) ? 1 : 0;
    if (!big) { NC = 1; T = EE; msgOff = OFF_BLKH; }
    short* msg = (short*)(ws + msgOff);

    int *cntB, *relStartB, *cursorB, *bS, *cesS, *blkSum;
    if (big) {
        int* ctl = (int*)(ws + OFF_CTL);
        cntB = ctl; relStartB = ctl + 4864; cursorB = ctl + 9728;
        bS = ctl + 19456; cesS = ctl + 19520; blkSum = ctl + 19584;
    } else {
        int* ctl = (int*)(ws + OFF_CNT);
        cntB = ctl; relStartB = ctl + 256; cursorB = ctl + 512;
        bS = ctl + 976; cesS = ctl + 992; blkSum = ctl + 1000;
    }

    const int NBLK = (NN + 255) / 256;  // 391

    hipMemsetAsync(deg8, 0, (size_t)NN * RR, stream);
    if (big) {
        hipMemsetAsync(dstCnt, 0, (size_t)NN * 4, stream);
        hipMemsetAsync(cur, 0, (size_t)NN * 4, stream);
    } else {
        hipMemsetAsync((void*)cntB, 0, 4096, stream);
    }

    kCount<<<(EE + 255) / 256, 256, 0, stream>>>(ei, et, deg8, dstCnt, big);
    if (big) {
        kScanBlk<<<NBLK, 256, 0, stream>>>(dstCnt, dstStart, blkSum);
        kScanTop<<<1, 512, 0, stream>>>(blkSum, NBLK);
        kScanAdd<<<NBLK, 256, 0, stream>>>(dstCnt, dstStart, blkSum);
        kChunk<<<1, 64, 0, stream>>>(dstStart, bS, cesS, NC, (int)T);
        // contention-free 2-pass counting sort
        kHist<<<NPART, 256, 0, stream>>>(ei, et, bS, blockHist, NC);
        kScanP<<<NC * RR, NPART, 0, stream>>>(blockHist, cntB, NC * RR);
        kScanB<<<1, 256, 0, stream>>>(cntB, relStartB, cursorB, NC * RR);
        kPart<<<NPART, 256, 0, stream>>>(ei, et, deg8, bS, relStartB, blockHist,
                                         dstStart, cur, norm, sortedE, posDst, NC);
    } else {
        kCountB<<<(EE + 255) / 256, 256, 0, stream>>>(ei, et, bS, cntB, NC);
        kScanB<<<1, 256, 0, stream>>>(cntB, relStartB, cursorB, NC * RR);
        kNormScatter<<<(EE + 255) / 256, 256, 0, stream>>>(ei, et, deg8, bS, cursorB,
                                                           dstStart, cur, norm, sortedE,
                                                           posDst, NC, big);
    }
    kConvert<<<(NN * XP + 255) / 256, 256, 0, stream>>>(emb, xb, 0);

    for (int l = 0; l < LL; ++l) {
        kW<<<dim3(7, 26), 256, 0, stream>>>(comp + l * RR * BB,
                                            bases + (size_t)l * BB * DD * DD, Wt);
        kRootT<<<(NP * KP + 255) / 256, 256, 0, stream>>>(root + l * DD * DD, rootT);
        kRootGemm<<<(NN + RT - 1) / RT, 256, 0, stream>>>(xb, rootT, bias + l * DD, y);
        if (big) {
            for (int c = 0; c < NC; ++c) {
                kMsgP<0><<<RR * NSPL, 512, 0, stream>>>(ei, xb, Wt, relStartB, sortedE,
                                                        norm, posDst, cesS, y, msg, c);
                kAgg<<<2048, 256, 0, stream>>>(msg, dstStart, bS, cesS, y, c);
            }
            if (l == 0)
                kConvert<<<(NN * XP + 255) / 256, 256, 0, stream>>>(y, xb, 0);
        } else {
            kMsgP<1><<<RR * NSPL, 512, 0, stream>>>(ei, xb, Wt, relStartB, sortedE,
                                                    norm, posDst, cesS, y, msg, 0);
            if (l == 0) kConvert<<<(NN * XP + 255) / 256, 256, 0, stream>>>(y, xb, 1);
            else        kRelu<<<(NN * DD + 255) / 256, 256, 0, stream>>>(y);
        }
    }
}